// Round 1
// baseline (591.521 us; speedup 1.0000x reference)
//
#include <hip/hip_runtime.h>
#include <hip/hip_bf16.h>

typedef __attribute__((ext_vector_type(8))) short bf16x8;
typedef __attribute__((ext_vector_type(4))) float f32x4;

#define N_TOK 1024
#define HEADS 8
#define DIM_HEAD 64
#define BATCH 8
#define DIMM 512
#define INNER 512
#define QKV_COLS 1536

__device__ inline short f2bf(float f) {
  union { float f; unsigned u; } v;
  v.f = f;
  unsigned r = v.u + 0x7fffu + ((v.u >> 16) & 1u);  // RNE
  return (short)(r >> 16);
}

// ---------------- elementwise fp32 -> bf16 ----------------
__global__ void cvt_bf16_kernel(const float* __restrict__ in, short* __restrict__ out, int n) {
  int i = (blockIdx.x * 256 + threadIdx.x) * 4;
  if (i >= n) return;
  float4 v = *(const float4*)&in[i];
  short4 o;
  o.x = f2bf(v.x); o.y = f2bf(v.y); o.z = f2bf(v.z); o.w = f2bf(v.w);
  *(short4*)&out[i] = o;
}

// ---------------- transpose + convert: W[K][Nc] -> Wt[Nc][K] bf16 ----------------
__global__ void tr_cvt_kernel(const float* __restrict__ W, short* __restrict__ Wt, int K, int Nc) {
  int id = blockIdx.x * 256 + threadIdx.x;
  if (id >= K * Nc) return;
  int n = id % Nc, k = id / Nc;
  Wt[n * K + k] = f2bf(W[id]);
}

// ---------------- bf16 MFMA GEMM: C[M][Nc] = A[M][K] * Bt[Nc][K]^T ----------------
template<int OUT_BF16, int ADD_BIAS>
__global__ __launch_bounds__(256)
void gemm_kernel(const short* __restrict__ A, const short* __restrict__ Bt,
                 void* __restrict__ C, const float* __restrict__ bias,
                 int M, int Nc, int K)
{
  __shared__ short Ash[128][40];   // pitch 40 bf16 = 80B -> 2-way bank alias only
  __shared__ short Bsh[128][40];
  const int t = threadIdx.x;
  const int lane = t & 63, wave = t >> 6;
  const int wm = wave >> 1, wn = wave & 1;
  const int m0 = blockIdx.y * 128, n0 = blockIdx.x * 128;
  f32x4 acc[4][4] = {};
  for (int k0 = 0; k0 < K; k0 += 32) {
    __syncthreads();
    #pragma unroll
    for (int c = 0; c < 2; ++c) {
      int id = c * 256 + t;
      int row = id >> 2, kc = (id & 3) * 8;
      *(int4*)&Ash[row][kc] = *(const int4*)&A[(size_t)(m0 + row) * K + k0 + kc];
      *(int4*)&Bsh[row][kc] = *(const int4*)&Bt[(size_t)(n0 + row) * K + k0 + kc];
    }
    __syncthreads();
    bf16x8 af[4], bfr[4];
    #pragma unroll
    for (int m = 0; m < 4; ++m)
      af[m] = *(const bf16x8*)&Ash[wm*64 + m*16 + (lane & 15)][(lane >> 4) * 8];
    #pragma unroll
    for (int n = 0; n < 4; ++n)
      bfr[n] = *(const bf16x8*)&Bsh[wn*64 + n*16 + (lane & 15)][(lane >> 4) * 8];
    #pragma unroll
    for (int m = 0; m < 4; ++m)
      #pragma unroll
      for (int n = 0; n < 4; ++n)
        acc[m][n] = __builtin_amdgcn_mfma_f32_16x16x32_bf16(af[m], bfr[n], acc[m][n], 0, 0, 0);
  }
  const int r0 = (lane >> 4) * 4, c0 = lane & 15;
  #pragma unroll
  for (int m = 0; m < 4; ++m)
    #pragma unroll
    for (int n = 0; n < 4; ++n) {
      int col = n0 + wn*64 + n*16 + c0;
      float bv = ADD_BIAS ? bias[col] : 0.f;
      #pragma unroll
      for (int r = 0; r < 4; ++r) {
        int row = m0 + wm*64 + m*16 + r0 + r;
        float v = acc[m][n][r] + bv;
        if (OUT_BF16) ((short*)C)[(size_t)row * Nc + col] = f2bf(v);
        else          ((float*)C)[(size_t)row * Nc + col] = v;
      }
    }
}

// ---------------- row reduction helper (16-lane groups -> cross-wave) ----------------
template<int IS_MAX>
__device__ inline void reduce4(float (&loc)[4], float (&red)[4][16], int wave, int lane) {
  #pragma unroll
  for (int off = 1; off < 16; off <<= 1)
    #pragma unroll
    for (int r = 0; r < 4; ++r) {
      float o = __shfl_xor(loc[r], off);
      loc[r] = IS_MAX ? fmaxf(loc[r], o) : (loc[r] + o);
    }
  __syncthreads();
  if ((lane & 15) == 0)
    #pragma unroll
    for (int r = 0; r < 4; ++r) red[wave][(lane >> 4) * 4 + r] = loc[r];
  __syncthreads();
  #pragma unroll
  for (int r = 0; r < 4; ++r) {
    int rl = (lane >> 4) * 4 + r;
    float a = red[0][rl], b = red[1][rl], c = red[2][rl], d = red[3][rl];
    loc[r] = IS_MAX ? fmaxf(fmaxf(a, b), fmaxf(c, d)) : (a + b + c + d);
  }
}

// ---------------- fused attention: one block = (b, h, 16 query rows) ----------------
__global__ __launch_bounds__(256)
void attn_kernel(const short* __restrict__ qkv,
                 const float* __restrict__ rel_table,   // [3969][8]
                 const float* __restrict__ headsita,    // [8]
                 const int* __restrict__ rpe_p,
                 float* __restrict__ out2,              // softmax(dots0)  [B,H,N,N]
                 short* __restrict__ Obuf)              // [B*N][512] bf16
{
  __shared__ short Qs[16][72];
  __shared__ short KVs[64][72];    // K tile (QK phase), then V^T tile (PV phase)
  __shared__ short Ps[16][1032];   // attn probs bf16
  __shared__ float red[4][16];

  const int t = threadIdx.x;
  const int lane = t & 63, wave = t >> 6;
  const int i0 = blockIdx.x * 16;
  const int h  = blockIdx.y;
  const int b  = blockIdx.z;
  const int rg = lane >> 4;        // row group 0..3
  const int cl = lane & 15;        // frag col
  const size_t rowbase = (size_t)b * N_TOK;

  // ---- stage Q (16 x 64 bf16) ----
  if (t < 128) {
    int row = t >> 3, kc = (t & 7) * 8;
    *(int4*)&Qs[row][kc] =
      *(const int4*)&qkv[(rowbase + i0 + row) * QKV_COLS + h * DIM_HEAD + kc];
  }
  __syncthreads();
  bf16x8 qf0 = *(const bf16x8*)&Qs[cl][rg * 8];
  bf16x8 qf1 = *(const bf16x8*)&Qs[cl][32 + rg * 8];

  f32x4 sc[16];
  #pragma unroll
  for (int i = 0; i < 16; ++i) sc[i] = (f32x4){0.f, 0.f, 0.f, 0.f};

  // ---- QK^T over 16 column tiles of 64 ----
  #pragma unroll
  for (int tt = 0; tt < 16; ++tt) {
    __syncthreads();
    #pragma unroll
    for (int c = 0; c < 2; ++c) {
      int id = c * 256 + t;
      int j = id >> 3, kc = (id & 7) * 8;
      *(int4*)&KVs[j][kc] =
        *(const int4*)&qkv[(rowbase + tt * 64 + j) * QKV_COLS + INNER + h * DIM_HEAD + kc];
    }
    __syncthreads();
    bf16x8 kb0 = *(const bf16x8*)&KVs[wave * 16 + cl][rg * 8];
    bf16x8 kb1 = *(const bf16x8*)&KVs[wave * 16 + cl][32 + rg * 8];
    sc[tt] = __builtin_amdgcn_mfma_f32_16x16x32_bf16(qf0, kb0, sc[tt], 0, 0, 0);
    sc[tt] = __builtin_amdgcn_mfma_f32_16x16x32_bf16(qf1, kb1, sc[tt], 0, 0, 0);
  }

  // scale = 1/sqrt(64)
  #pragma unroll
  for (int tt = 0; tt < 16; ++tt)
    #pragma unroll
    for (int r = 0; r < 4; ++r) sc[tt][r] *= 0.125f;

  // ---- softmax(dots0) -> out2 ----
  float mx0[4] = {-1e30f, -1e30f, -1e30f, -1e30f};
  #pragma unroll
  for (int tt = 0; tt < 16; ++tt)
    #pragma unroll
    for (int r = 0; r < 4; ++r) mx0[r] = fmaxf(mx0[r], sc[tt][r]);
  reduce4<1>(mx0, red, wave, lane);

  float sm0[4] = {0.f, 0.f, 0.f, 0.f};
  #pragma unroll
  for (int tt = 0; tt < 16; ++tt)
    #pragma unroll
    for (int r = 0; r < 4; ++r) sm0[r] += __expf(sc[tt][r] - mx0[r]);
  reduce4<0>(sm0, red, wave, lane);

  #pragma unroll
  for (int r = 0; r < 4; ++r) {
    float iv = 1.f / sm0[r];
    size_t orow = ((size_t)(b * HEADS + h) * N_TOK + i0 + rg * 4 + r) * N_TOK;
    #pragma unroll
    for (int tt = 0; tt < 16; ++tt)
      out2[orow + tt * 64 + wave * 16 + cl] = __expf(sc[tt][r] - mx0[r]) * iv;
  }

  // ---- add relative-position bias + gaussian RPE ----
  if (rpe_p[0]) {
    float th = headsita[h];
    float factor = 1.f / (2.f * th * th + 1e-10f);
    #pragma unroll
    for (int r = 0; r < 4; ++r) {
      int i = i0 + rg * 4 + r;
      int ri = i >> 5, ci = i & 31;
      #pragma unroll
      for (int tt = 0; tt < 16; ++tt) {
        int j = tt * 64 + wave * 16 + cl;
        int dr = ri - (j >> 5), dc = ci - (j & 31);
        int idx = (dr + 31) * 63 + (dc + 31);
        float dis = (float)(dr * dr + dc * dc) * (1.0f / 1024.0f);
        sc[tt][r] += rel_table[idx * HEADS + h] + 0.01f * __expf(-factor * dis);
      }
    }
  }

  // ---- softmax(dots) -> Ps (bf16, normalized) ----
  float mx1[4] = {-1e30f, -1e30f, -1e30f, -1e30f};
  #pragma unroll
  for (int tt = 0; tt < 16; ++tt)
    #pragma unroll
    for (int r = 0; r < 4; ++r) mx1[r] = fmaxf(mx1[r], sc[tt][r]);
  reduce4<1>(mx1, red, wave, lane);

  float sm1[4] = {0.f, 0.f, 0.f, 0.f};
  #pragma unroll
  for (int tt = 0; tt < 16; ++tt)
    #pragma unroll
    for (int r = 0; r < 4; ++r) sm1[r] += __expf(sc[tt][r] - mx1[r]);
  reduce4<0>(sm1, red, wave, lane);

  #pragma unroll
  for (int r = 0; r < 4; ++r) {
    float iv = 1.f / sm1[r];
    #pragma unroll
    for (int tt = 0; tt < 16; ++tt)
      Ps[rg * 4 + r][tt * 64 + wave * 16 + cl] = f2bf(__expf(sc[tt][r] - mx1[r]) * iv);
  }

  // ---- PV: O[16][64] = P[16][1024] @ V[1024][64] ----
  f32x4 oacc = (f32x4){0.f, 0.f, 0.f, 0.f};
  #pragma unroll
  for (int tt = 0; tt < 16; ++tt) {
    __syncthreads();
    #pragma unroll
    for (int c = 0; c < 2; ++c) {
      int id = c * 256 + t;
      int j = id >> 3, kc = (id & 7) * 8;
      int4 v4 = *(const int4*)&qkv[(rowbase + tt * 64 + j) * QKV_COLS + 2 * INNER + h * DIM_HEAD + kc];
      const short* vs = (const short*)&v4;
      #pragma unroll
      for (int e = 0; e < 8; ++e) KVs[kc + e][j] = vs[e];   // transpose to [d][j]
    }
    __syncthreads();
    bf16x8 pa0 = *(const bf16x8*)&Ps[cl][tt * 64 + rg * 8];
    bf16x8 pa1 = *(const bf16x8*)&Ps[cl][tt * 64 + 32 + rg * 8];
    bf16x8 vb0 = *(const bf16x8*)&KVs[wave * 16 + cl][rg * 8];
    bf16x8 vb1 = *(const bf16x8*)&KVs[wave * 16 + cl][32 + rg * 8];
    oacc = __builtin_amdgcn_mfma_f32_16x16x32_bf16(pa0, vb0, oacc, 0, 0, 0);
    oacc = __builtin_amdgcn_mfma_f32_16x16x32_bf16(pa1, vb1, oacc, 0, 0, 0);
  }

  #pragma unroll
  for (int r = 0; r < 4; ++r) {
    int i = i0 + rg * 4 + r;
    Obuf[(rowbase + i) * INNER + h * DIM_HEAD + wave * 16 + cl] = f2bf(oacc[r]);
  }
}

extern "C" void kernel_launch(void* const* d_in, const int* in_sizes, int n_in,
                              void* d_out, int out_size, void* d_ws, size_t ws_size,
                              hipStream_t stream) {
  const float* x    = (const float*)d_in[0];
  const float* Wqkv = (const float*)d_in[1];
  const float* Wout = (const float*)d_in[2];
  const float* bout = (const float*)d_in[3];
  const float* rel  = (const float*)d_in[4];
  const float* sita = (const float*)d_in[5];
  const int*   rpe  = (const int*)d_in[6];

  char* ws = (char*)d_ws;
  short* xb   = (short*)(ws);                 //  8 MB  x bf16 [8192][512]
  short* WqT  = (short*)(ws + 8388608);       //  1.5MB W_qkv^T bf16 [1536][512]
  short* WoT  = (short*)(ws + 9961472);       //  0.5MB W_out^T bf16 [512][512]
  short* qkv  = (short*)(ws + 10485760);      // 24 MB  qkv bf16 [8192][1536]
  short* Obuf = (short*)(ws + 35651584);      //  8 MB  attn-out bf16 [8192][512]

  float* out1 = (float*)d_out;
  float* out2 = out1 + (size_t)BATCH * N_TOK * DIMM;

  hipLaunchKernelGGL(cvt_bf16_kernel, dim3(4096), dim3(256), 0, stream,
                     x, xb, BATCH * N_TOK * DIMM);
  hipLaunchKernelGGL(tr_cvt_kernel, dim3((512 * 1536 + 255) / 256), dim3(256), 0, stream,
                     Wqkv, WqT, 512, 1536);
  hipLaunchKernelGGL(tr_cvt_kernel, dim3((512 * 512 + 255) / 256), dim3(256), 0, stream,
                     Wout, WoT, 512, 512);
  hipLaunchKernelGGL((gemm_kernel<1, 0>), dim3(12, 64), dim3(256), 0, stream,
                     xb, WqT, (void*)qkv, (const float*)nullptr, 8192, 1536, 512);
  hipLaunchKernelGGL(attn_kernel, dim3(64, 8, 8), dim3(256), 0, stream,
                     qkv, rel, sita, rpe, out2, Obuf);
  hipLaunchKernelGGL((gemm_kernel<0, 1>), dim3(4, 64), dim3(256), 0, stream,
                     Obuf, WoT, d_out, bout, 8192, 512, 512);
}